// Round 2
// baseline (144.112 us; speedup 1.0000x reference)
//
#include <hip/hip_runtime.h>
#include <hip/hip_fp16.h>
#include <math.h>

#define SS 2048
#define DD 512
#define NH 8
#define HD 64

typedef __attribute__((ext_vector_type(8))) short frag_ab;   // 8 fp16
typedef __attribute__((ext_vector_type(4))) float frag_cd;   // 4 fp32

static __device__ inline unsigned int pack_h2(float x, float y) {
    __half2 t = __floats2half2_rn(x, y);   // x -> low half
    return *(unsigned int*)&t;
}

// ---------- GEMM: q_h = fp16(x @ Wq); B transposed in-register during staging ----------
__global__ __launch_bounds__(256, 4) void gemm_kernel(const float* __restrict__ x,
                                                      const float* __restrict__ w,
                                                      unsigned short* __restrict__ q) {
    __shared__ __align__(16) unsigned short Ah[2][64 * 72];  // [m][k]
    __shared__ __align__(16) unsigned short Bt[2][64 * 72];  // [n][k]
    const int tid = threadIdx.x;
    const int lane = tid & 63, wv = tid >> 6;
    const int a = lane & 15, g = lane >> 4;
    const int bm = blockIdx.x, bn = blockIdx.y;

    frag_cd acc[4] = {};
    const int asr = tid >> 4;
    const int ac4 = (tid & 15) * 4;
    const int bnn = (tid & 31) * 2;
    const int bkk = (tid >> 5) * 8;

    float4 av[4];
    float2 bv[8];
    #pragma unroll
    for (int p = 0; p < 4; ++p)
        av[p] = *(const float4*)(x + (size_t)(bm * 64 + asr + p * 16) * 512 + ac4);
    #pragma unroll
    for (int j = 0; j < 8; ++j)
        bv[j] = *(const float2*)(w + (size_t)(bkk + j) * 512 + bn * 64 + bnn);

    for (int it = 0; it < 8; ++it) {
        const int cur = it & 1;
        #pragma unroll
        for (int p = 0; p < 4; ++p) {
            uint2 hh = { pack_h2(av[p].x, av[p].y), pack_h2(av[p].z, av[p].w) };
            *(uint2*)&Ah[cur][(asr + p * 16) * 72 + ac4] = hh;
        }
        {
            unsigned int t0[4], t1[4];
            #pragma unroll
            for (int j = 0; j < 4; ++j) {
                t0[j] = pack_h2(bv[2 * j].x, bv[2 * j + 1].x);
                t1[j] = pack_h2(bv[2 * j].y, bv[2 * j + 1].y);
            }
            *(uint4*)&Bt[cur][bnn * 72 + bkk]       = *(uint4*)t0;
            *(uint4*)&Bt[cur][(bnn + 1) * 72 + bkk] = *(uint4*)t1;
        }
        __syncthreads();
        if (it < 7) {
            const int k0 = (it + 1) * 64;
            #pragma unroll
            for (int p = 0; p < 4; ++p)
                av[p] = *(const float4*)(x + (size_t)(bm * 64 + asr + p * 16) * 512 + k0 + ac4);
            #pragma unroll
            for (int j = 0; j < 8; ++j)
                bv[j] = *(const float2*)(w + (size_t)(k0 + bkk + j) * 512 + bn * 64 + bnn);
        }
        #pragma unroll
        for (int kh = 0; kh < 2; ++kh) {
            const frag_ab bf = *(const frag_ab*)&Bt[cur][(wv * 16 + a) * 72 + kh * 32 + g * 8];
            #pragma unroll
            for (int mt = 0; mt < 4; ++mt) {
                const frag_ab af = *(const frag_ab*)&Ah[cur][(mt * 16 + a) * 72 + kh * 32 + g * 8];
                acc[mt] = __builtin_amdgcn_mfma_f32_16x16x32_f16(af, bf, acc[mt], 0, 0, 0);
            }
        }
    }
    #pragma unroll
    for (int mt = 0; mt < 4; ++mt)
        #pragma unroll
        for (int r = 0; r < 4; ++r) {
            const int m = bm * 64 + mt * 16 + g * 4 + r;
            const int n = bn * 64 + wv * 16 + a;
            __half hv = __float2half_rn(acc[mt][r]);
            q[(size_t)m * 512 + n] = *(unsigned short*)&hv;
        }
}

// ---------- Flash attention, R12 = R11 structure with shuffle-based P transpose ----------
// Grid 1024 = 32(qt of 64 q-rows) x 8(h) x 4(b); 512 threads = 8 waves =
// 4 q-groups(16 rows) x 2 key-halves.
//  * Pq LDS eliminated: P redistributed in-register.  The permutation is two
//    transpositions: (reg-pair-bit i0 <-> lane-bit5), then (i0 <-> lane-bit4).
//    R11 used v_permlane*_swap whose HW swap orientation proved untrustworthy
//    (absmax 4.19); R12 implements the SAME traced permutation with
//    __shfl_xor + cndmask selects (pull semantics, unambiguous):
//      out = b ? ph0 : ph1; t = shfl_xor(out, m); ph0 = b ? t : ph0; ph1 = b ? ph1 : t;
//    per pair = 1 bpermute + 3 selects; 8 bpermute + 24 sel per iter total.
//  * LDS 71680 -> 34816 B => 4 blocks/CU (grid exactly 4/CU), 32 waves/CU.
//  * Vt swizzle s(f) = (f>>1)&7 on write AND read (conflict-free both sides).
__global__ __launch_bounds__(512, 8) void attn_kernel(const __half* __restrict__ qg,
                                                      float* __restrict__ out) {
    __shared__ __align__(16) unsigned short Kt[2][64 * 72];   // [kv][key][f]     18.4 KB
    __shared__ __align__(16) unsigned short Vt[2][64 * 64];   // [kv][f][key] swz 16 KB

    const int tid = threadIdx.x;
    const int lane = tid & 63, wv = tid >> 6;
    const int a = lane & 15, g = lane >> 4;
    const int qq = wv & 3;            // q group (16 rows)
    const int kv = wv >> 2;           // key half (1024 keys)
    const int bid = blockIdx.x;       // 1024 = 32(qt) * 8(h) * 4(b)
    const int qt = bid & 31;
    const int h  = (bid >> 5) & 7;
    const int b  = bid >> 8;

    const unsigned short* qbh = (const unsigned short*)qg + (size_t)b * SS * DD + h * HD;
    const int qrow0 = qt * 64 + qq * 16;

    // Q B-fragments, pre-scaled by 0.125*log2(e)
    frag_ab qf[2];
    const __half2 qsc = __float2half2_rn(0.18033688011112042f);
    #pragma unroll
    for (int kh = 0; kh < 2; ++kh) {
        frag_ab t = *(const frag_ab*)(qbh + (size_t)(qrow0 + a) * DD + kh * 32 + g * 8);
        __half2* phh = (__half2*)&t;
        #pragma unroll
        for (int i = 0; i < 4; ++i) phh[i] = __hmul2(phh[i], qsc);
        qf[kh] = t;
    }

    frag_cd oacc[4] = {};             // [ft] -> O^T[feature][q=a]
    float lsum = 0.f;

    // staging: threads 0-255 stage key-half 0, 256-511 half 1 (== own wave's kv)
    const int t8 = tid & 255;
    const int f0 = (t8 & 31) * 2;     // feature column (even)
    const int u8 = t8 >> 5;           // key chunk 0..7
    const int r0 = u8 * 8;
    const int keybase = (tid >> 8) * 1024;
    unsigned short* Ks = Kt[tid >> 8];
    unsigned short* Vs = Vt[tid >> 8];
    const int vsw = (u8 ^ (t8 & 7)) << 3;   // s(f) = (f>>1)&7 ; (f0>>1)&7 == t8&7

    unsigned int d[8];
    #pragma unroll
    for (int k = 0; k < 8; ++k)
        d[k] = *(const unsigned int*)(qbh + (size_t)(keybase + r0 + k) * DD + f0);

    const unsigned short* Kc = Kt[kv];
    const unsigned short* Vc = Vt[kv];
    const float coff = -11.541560327111707f;   // -8*log2(e): p = 2^(s' + coff) = e^(s-8)
    const bool hi32 = (lane & 32) != 0;        // lane bit 5
    const bool hi16 = (lane & 16) != 0;        // lane bit 4

    for (int it = 0; it < 16; ++it) {
        __syncthreads();              // all waves done reading previous tiles
        #pragma unroll
        for (int k = 0; k < 8; ++k)   // K key-major, stride 72 (floor-rate)
            *(unsigned int*)&Ks[(r0 + k) * 72 + f0] = d[k];
        {                             // V^T feature-major, stride 64 + XOR swizzle
            unsigned int vlo[4], vhi[4];
            #pragma unroll
            for (int j = 0; j < 4; ++j) {
                vlo[j] = (d[2 * j] & 0xFFFFu) | (d[2 * j + 1] << 16);
                vhi[j] = (d[2 * j] >> 16)     | (d[2 * j + 1] & 0xFFFF0000u);
            }
            *(uint4*)&Vs[f0 * 64 + vsw]       = *(uint4*)vlo;   // same s for f0,f0+1
            *(uint4*)&Vs[(f0 + 1) * 64 + vsw] = *(uint4*)vhi;
        }
        __syncthreads();              // staged tiles visible

        if (it + 1 < 16) {            // prefetch next tile (overlaps compute)
            const int kb = keybase + (it + 1) * 64;
            #pragma unroll
            for (int k = 0; k < 8; ++k)
                d[k] = *(const unsigned int*)(qbh + (size_t)(kb + r0 + k) * DD + f0);
        }

        // ---- S^T = K . Q^T (C-init = exp offset), exp2, pack in regs ----
        unsigned int ph[4][2];        // [kt][w]: pack(p[2w], p[2w+1]) keys kt*16+4g+{2w,2w+1}
        #pragma unroll
        for (int kt = 0; kt < 4; ++kt) {
            const frag_ab ka0 = *(const frag_ab*)&Kc[(kt * 16 + a) * 72 + g * 8];
            const frag_ab ka1 = *(const frag_ab*)&Kc[(kt * 16 + a) * 72 + 32 + g * 8];
            frag_cd c = {coff, coff, coff, coff};
            c = __builtin_amdgcn_mfma_f32_16x16x32_f16(ka0, qf[0], c, 0, 0, 0);
            c = __builtin_amdgcn_mfma_f32_16x16x32_f16(ka1, qf[1], c, 0, 0, 0);
            const float p0 = __builtin_amdgcn_exp2f(c[0]);
            const float p1 = __builtin_amdgcn_exp2f(c[1]);
            const float p2 = __builtin_amdgcn_exp2f(c[2]);
            const float p3 = __builtin_amdgcn_exp2f(c[3]);
            lsum += (p0 + p1) + (p2 + p3);
            ph[kt][0] = pack_h2(p0, p1);
            ph[kt][1] = pack_h2(p2, p3);
        }
        // ---- in-register P transpose (shuffle version, orientation-safe) ----
        // round 1: transpose reg-pair-bit with lane bit5 (exchange across lane^32)
        #pragma unroll
        for (int w = 0; w < 2; ++w) {
            unsigned int s01 = hi32 ? ph[0][w] : ph[1][w];
            unsigned int t01 = __shfl_xor(s01, 32, 64);
            ph[0][w] = hi32 ? t01 : ph[0][w];
            ph[1][w] = hi32 ? ph[1][w] : t01;
            unsigned int s23 = hi32 ? ph[2][w] : ph[3][w];
            unsigned int t23 = __shfl_xor(s23, 32, 64);
            ph[2][w] = hi32 ? t23 : ph[2][w];
            ph[3][w] = hi32 ? ph[3][w] : t23;
        }
        // round 2: transpose reg-pair-bit with lane bit4 (exchange across lane^16)
        #pragma unroll
        for (int w = 0; w < 2; ++w) {
            unsigned int s01 = hi16 ? ph[0][w] : ph[1][w];
            unsigned int t01 = __shfl_xor(s01, 16, 64);
            ph[0][w] = hi16 ? t01 : ph[0][w];
            ph[1][w] = hi16 ? ph[1][w] : t01;
            unsigned int s23 = hi16 ? ph[2][w] : ph[3][w];
            unsigned int t23 = __shfl_xor(s23, 16, 64);
            ph[2][w] = hi16 ? t23 : ph[2][w];
            ph[3][w] = hi16 ? ph[3][w] : t23;
        }
        // ---- O^T += V^T . P^T ----
        #pragma unroll
        for (int kh = 0; kh < 2; ++kh) {
            __attribute__((aligned(16))) unsigned int pw4[4] =
                { ph[2 * kh][0], ph[2 * kh][1], ph[2 * kh + 1][0], ph[2 * kh + 1][1] };
            const frag_ab pb = *(const frag_ab*)pw4;
            #pragma unroll
            for (int ft = 0; ft < 4; ++ft) {
                const frag_ab va = *(const frag_ab*)
                    &Vc[(ft * 16 + a) * 64 + (((4 * kh + g) ^ ((a >> 1) & 7)) << 3)];
                oacc[ft] = __builtin_amdgcn_mfma_f32_16x16x32_f16(va, pb, oacc[ft], 0, 0, 0);
            }
        }
    }

    // ---- in-block combine: kv=1 -> LDS; kv=0 adds, normalizes, writes ----
    lsum += __shfl_xor(lsum, 16, 64);
    lsum += __shfl_xor(lsum, 32, 64);
    __syncthreads();                              // all tile reads done; LDS reusable
    float* Obuf = (float*)&Kt[0][0];              // [qq][f 64][q 16+1 pad] = 17.4 KB
    float* Lbuf = (float*)&Vt[0][0];              // [qq][q 16]
    if (kv == 1) {
        #pragma unroll
        for (int ft = 0; ft < 4; ++ft)
            #pragma unroll
            for (int r = 0; r < 4; ++r)
                Obuf[qq * 1088 + (ft * 16 + g * 4 + r) * 17 + a] = oacc[ft][r];
        if (g == 0) Lbuf[qq * 16 + a] = lsum;
    }
    __syncthreads();
    if (kv == 0) {
        const float inv = 1.f / (lsum + Lbuf[qq * 16 + a]);
        float* op = out + ((size_t)b * SS + qrow0 + a) * DD + h * HD;
        #pragma unroll
        for (int ft = 0; ft < 4; ++ft) {
            const int fb = ft * 16 + g * 4;
            float4 vv = {
                (oacc[ft][0] + Obuf[qq * 1088 + (fb + 0) * 17 + a]) * inv,
                (oacc[ft][1] + Obuf[qq * 1088 + (fb + 1) * 17 + a]) * inv,
                (oacc[ft][2] + Obuf[qq * 1088 + (fb + 2) * 17 + a]) * inv,
                (oacc[ft][3] + Obuf[qq * 1088 + (fb + 3) * 17 + a]) * inv };
            *(float4*)(op + fb) = vv;
        }
    }
}

extern "C" void kernel_launch(void* const* d_in, const int* in_sizes, int n_in,
                              void* d_out, int out_size, void* d_ws, size_t ws_size,
                              hipStream_t stream) {
    const float* x  = (const float*)d_in[0];
    const float* wq = (const float*)d_in[1];
    float* out = (float*)d_out;
    unsigned short* q_h = (unsigned short*)d_ws;   // 8 MB

    dim3 ggrid(128, 8);
    gemm_kernel<<<ggrid, 256, 0, stream>>>(x, wq, q_h);
    attn_kernel<<<1024, 512, 0, stream>>>((const __half*)q_h, out);
}

// Round 3
// 128.610 us; speedup vs baseline: 1.1205x; 1.1205x over previous
//
#include <hip/hip_runtime.h>
#include <hip/hip_fp16.h>
#include <math.h>

#define SS 2048
#define DD 512
#define NH 8
#define HD 64

typedef __attribute__((ext_vector_type(8))) short frag_ab;   // 8 fp16
typedef __attribute__((ext_vector_type(4))) float frag_cd;   // 4 fp32

static __device__ inline unsigned int pack_h2(float x, float y) {
    __half2 t = __floats2half2_rn(x, y);   // x -> low half
    return *(unsigned int*)&t;
}

// ---------- GEMM: q_h = fp16(x @ Wq); B transposed in-register during staging ----------
__global__ __launch_bounds__(256, 4) void gemm_kernel(const float* __restrict__ x,
                                                      const float* __restrict__ w,
                                                      unsigned short* __restrict__ q) {
    __shared__ __align__(16) unsigned short Ah[2][64 * 72];  // [m][k]
    __shared__ __align__(16) unsigned short Bt[2][64 * 72];  // [n][k]
    const int tid = threadIdx.x;
    const int lane = tid & 63, wv = tid >> 6;
    const int a = lane & 15, g = lane >> 4;
    const int bm = blockIdx.x, bn = blockIdx.y;

    frag_cd acc[4] = {};
    const int asr = tid >> 4;
    const int ac4 = (tid & 15) * 4;
    const int bnn = (tid & 31) * 2;
    const int bkk = (tid >> 5) * 8;

    float4 av[4];
    float2 bv[8];
    #pragma unroll
    for (int p = 0; p < 4; ++p)
        av[p] = *(const float4*)(x + (size_t)(bm * 64 + asr + p * 16) * 512 + ac4);
    #pragma unroll
    for (int j = 0; j < 8; ++j)
        bv[j] = *(const float2*)(w + (size_t)(bkk + j) * 512 + bn * 64 + bnn);

    for (int it = 0; it < 8; ++it) {
        const int cur = it & 1;
        #pragma unroll
        for (int p = 0; p < 4; ++p) {
            uint2 hh = { pack_h2(av[p].x, av[p].y), pack_h2(av[p].z, av[p].w) };
            *(uint2*)&Ah[cur][(asr + p * 16) * 72 + ac4] = hh;
        }
        {
            unsigned int t0[4], t1[4];
            #pragma unroll
            for (int j = 0; j < 4; ++j) {
                t0[j] = pack_h2(bv[2 * j].x, bv[2 * j + 1].x);
                t1[j] = pack_h2(bv[2 * j].y, bv[2 * j + 1].y);
            }
            *(uint4*)&Bt[cur][bnn * 72 + bkk]       = *(uint4*)t0;
            *(uint4*)&Bt[cur][(bnn + 1) * 72 + bkk] = *(uint4*)t1;
        }
        __syncthreads();
        if (it < 7) {
            const int k0 = (it + 1) * 64;
            #pragma unroll
            for (int p = 0; p < 4; ++p)
                av[p] = *(const float4*)(x + (size_t)(bm * 64 + asr + p * 16) * 512 + k0 + ac4);
            #pragma unroll
            for (int j = 0; j < 8; ++j)
                bv[j] = *(const float2*)(w + (size_t)(k0 + bkk + j) * 512 + bn * 64 + bnn);
        }
        #pragma unroll
        for (int kh = 0; kh < 2; ++kh) {
            const frag_ab bf = *(const frag_ab*)&Bt[cur][(wv * 16 + a) * 72 + kh * 32 + g * 8];
            #pragma unroll
            for (int mt = 0; mt < 4; ++mt) {
                const frag_ab af = *(const frag_ab*)&Ah[cur][(mt * 16 + a) * 72 + kh * 32 + g * 8];
                acc[mt] = __builtin_amdgcn_mfma_f32_16x16x32_f16(af, bf, acc[mt], 0, 0, 0);
            }
        }
    }
    #pragma unroll
    for (int mt = 0; mt < 4; ++mt)
        #pragma unroll
        for (int r = 0; r < 4; ++r) {
            const int m = bm * 64 + mt * 16 + g * 4 + r;
            const int n = bn * 64 + wv * 16 + a;
            __half hv = __float2half_rn(acc[mt][r]);
            q[(size_t)m * 512 + n] = *(unsigned short*)&hv;
        }
}

// ---------- Flash attention, R13 = R10 geometry + R12's verified wins ----------
// Grid 512 = 16(qt of 128 q-rows) x 8(h) x 4(b); 512 threads = 8 waves =
// 4 q-groups(32 rows, nt=0,1) x 2 key-halves (1024 keys each).
//  * Pq LDS eliminated (R12, numerics-verified): P redistributed in-register
//    via shuffle transpose (reg-pair-bit <-> lane-bit5, then <-> lane-bit4),
//    applied independently per nt.  8 bpermute + 24 sel per nt per iter.
//  * Vt write swizzle s(f) = (f>>1)&7 (R12 fix; R10's f&7 was 4-way
//    conflicted on the transposed V writes).
//  * LDS 71680 -> 34816 B (Kt 18432 + Vt 16384, epilogue Obuf/Lbuf overlaid).
//  * __launch_bounds__(512,4): cap 128 regs/wave -- R12's (512,8) forced a
//    32-VGPR split and spilled (WRITE_SIZE +8MB); R10 compiled clean at 64.
__global__ __launch_bounds__(512, 4) void attn_kernel(const __half* __restrict__ qg,
                                                      float* __restrict__ out) {
    __shared__ __align__(16) unsigned char LDSB[34816];
    unsigned short* KtB = (unsigned short*)LDSB;            // [2][64*72]  18432 B
    unsigned short* VtB = (unsigned short*)(LDSB + 18432);  // [2][64*64]  16384 B

    const int tid = threadIdx.x;
    const int lane = tid & 63, wv = tid >> 6;
    const int a = lane & 15, g = lane >> 4;
    const int qq = wv & 3;            // q group (32 rows)
    const int kv = wv >> 2;           // key half (1024 keys)
    const int bid = blockIdx.x;       // 512 = 16(qt) * 8(h) * 4(b)
    const int qt = bid & 15;
    const int h  = (bid >> 4) & 7;
    const int b  = bid >> 7;

    const unsigned short* qbh = (const unsigned short*)qg + (size_t)b * SS * DD + h * HD;
    const int qrow0 = qt * 128 + qq * 32;

    // Q B-fragments, pre-scaled by 0.125*log2(e)
    frag_ab qf[2][2];
    const __half2 qsc = __float2half2_rn(0.18033688011112042f);
    #pragma unroll
    for (int nt = 0; nt < 2; ++nt)
        #pragma unroll
        for (int kh = 0; kh < 2; ++kh) {
            frag_ab t = *(const frag_ab*)(qbh + (size_t)(qrow0 + nt * 16 + a) * DD + kh * 32 + g * 8);
            __half2* phh = (__half2*)&t;
            #pragma unroll
            for (int i = 0; i < 4; ++i) phh[i] = __hmul2(phh[i], qsc);
            qf[nt][kh] = t;
        }

    frag_cd oacc[4][2] = {};          // [ft][nt] -> O^T[feature][q=a]
    float lsum[2] = {0.f, 0.f};

    // staging: threads 0-255 stage key-half 0, 256-511 half 1 (== own wave's kv)
    const int t8 = tid & 255;
    const int f0 = (t8 & 31) * 2;     // feature column (even)
    const int u8 = t8 >> 5;           // key chunk 0..7
    const int r0 = u8 * 8;
    const int keybase = (tid >> 8) * 1024;
    unsigned short* Ks = KtB + (tid >> 8) * 4608;
    unsigned short* Vs = VtB + (tid >> 8) * 4096;
    const int vsw = (u8 ^ (t8 & 7)) << 3;   // s(f) = (f>>1)&7 ; (f0>>1)&7 == t8&7

    unsigned int d[8];
    #pragma unroll
    for (int k = 0; k < 8; ++k)
        d[k] = *(const unsigned int*)(qbh + (size_t)(keybase + r0 + k) * DD + f0);

    const unsigned short* Kc = KtB + kv * 4608;
    const unsigned short* Vc = VtB + kv * 4096;
    const float coff = -11.541560327111707f;   // -8*log2(e): p = 2^(s' + coff) = e^(s-8)
    const bool hi32 = (lane & 32) != 0;        // lane bit 5
    const bool hi16 = (lane & 16) != 0;        // lane bit 4

    for (int it = 0; it < 16; ++it) {
        __syncthreads();              // all waves done reading previous tiles
        #pragma unroll
        for (int k = 0; k < 8; ++k)   // K key-major, stride 72 (floor-rate)
            *(unsigned int*)&Ks[(r0 + k) * 72 + f0] = d[k];
        {                             // V^T feature-major, stride 64 + XOR swizzle
            unsigned int vlo[4], vhi[4];
            #pragma unroll
            for (int j = 0; j < 4; ++j) {
                vlo[j] = (d[2 * j] & 0xFFFFu) | (d[2 * j + 1] << 16);
                vhi[j] = (d[2 * j] >> 16)     | (d[2 * j + 1] & 0xFFFF0000u);
            }
            *(uint4*)&Vs[f0 * 64 + vsw]       = *(uint4*)vlo;   // same s for f0,f0+1
            *(uint4*)&Vs[(f0 + 1) * 64 + vsw] = *(uint4*)vhi;
        }
        __syncthreads();              // staged tiles visible

        if (it + 1 < 16) {            // prefetch next tile (overlaps compute)
            const int kb = keybase + (it + 1) * 64;
            #pragma unroll
            for (int k = 0; k < 8; ++k)
                d[k] = *(const unsigned int*)(qbh + (size_t)(kb + r0 + k) * DD + f0);
        }

        // ---- S^T = K . Q^T (C-init = exp offset), exp2, pack; per-nt transpose ----
        unsigned int ph[2][4][2];     // [nt][kt][w]
        #pragma unroll
        for (int kt = 0; kt < 4; ++kt) {
            const frag_ab ka0 = *(const frag_ab*)&Kc[(kt * 16 + a) * 72 + g * 8];
            const frag_ab ka1 = *(const frag_ab*)&Kc[(kt * 16 + a) * 72 + 32 + g * 8];
            #pragma unroll
            for (int nt = 0; nt < 2; ++nt) {
                frag_cd c = {coff, coff, coff, coff};
                c = __builtin_amdgcn_mfma_f32_16x16x32_f16(ka0, qf[nt][0], c, 0, 0, 0);
                c = __builtin_amdgcn_mfma_f32_16x16x32_f16(ka1, qf[nt][1], c, 0, 0, 0);
                const float p0 = __builtin_amdgcn_exp2f(c[0]);
                const float p1 = __builtin_amdgcn_exp2f(c[1]);
                const float p2 = __builtin_amdgcn_exp2f(c[2]);
                const float p3 = __builtin_amdgcn_exp2f(c[3]);
                lsum[nt] += (p0 + p1) + (p2 + p3);
                ph[nt][kt][0] = pack_h2(p0, p1);
                ph[nt][kt][1] = pack_h2(p2, p3);
            }
        }
        // ---- in-register P transpose (shuffle, orientation-safe; verified R12) ----
        #pragma unroll
        for (int nt = 0; nt < 2; ++nt) {
            #pragma unroll
            for (int w = 0; w < 2; ++w) {   // round 1: reg-pair-bit <-> lane bit5
                unsigned int s01 = hi32 ? ph[nt][0][w] : ph[nt][1][w];
                unsigned int t01 = __shfl_xor(s01, 32, 64);
                ph[nt][0][w] = hi32 ? t01 : ph[nt][0][w];
                ph[nt][1][w] = hi32 ? ph[nt][1][w] : t01;
                unsigned int s23 = hi32 ? ph[nt][2][w] : ph[nt][3][w];
                unsigned int t23 = __shfl_xor(s23, 32, 64);
                ph[nt][2][w] = hi32 ? t23 : ph[nt][2][w];
                ph[nt][3][w] = hi32 ? ph[nt][3][w] : t23;
            }
            #pragma unroll
            for (int w = 0; w < 2; ++w) {   // round 2: reg-pair-bit <-> lane bit4
                unsigned int s01 = hi16 ? ph[nt][0][w] : ph[nt][1][w];
                unsigned int t01 = __shfl_xor(s01, 16, 64);
                ph[nt][0][w] = hi16 ? t01 : ph[nt][0][w];
                ph[nt][1][w] = hi16 ? ph[nt][1][w] : t01;
                unsigned int s23 = hi16 ? ph[nt][2][w] : ph[nt][3][w];
                unsigned int t23 = __shfl_xor(s23, 16, 64);
                ph[nt][2][w] = hi16 ? t23 : ph[nt][2][w];
                ph[nt][3][w] = hi16 ? ph[nt][3][w] : t23;
            }
        }
        // ---- O^T += V^T . P^T ----
        #pragma unroll
        for (int kh = 0; kh < 2; ++kh) {
            frag_ab va[4];
            #pragma unroll
            for (int ft = 0; ft < 4; ++ft)
                va[ft] = *(const frag_ab*)
                    &Vc[(ft * 16 + a) * 64 + (((4 * kh + g) ^ ((a >> 1) & 7)) << 3)];
            #pragma unroll
            for (int nt = 0; nt < 2; ++nt) {
                __attribute__((aligned(16))) unsigned int pw4[4] =
                    { ph[nt][2 * kh][0], ph[nt][2 * kh][1],
                      ph[nt][2 * kh + 1][0], ph[nt][2 * kh + 1][1] };
                const frag_ab pb = *(const frag_ab*)pw4;
                #pragma unroll
                for (int ft = 0; ft < 4; ++ft)
                    oacc[ft][nt] = __builtin_amdgcn_mfma_f32_16x16x32_f16(va[ft], pb, oacc[ft][nt], 0, 0, 0);
            }
        }
    }

    // ---- in-block combine: kv=1 -> LDS; kv=0 adds, normalizes, writes ----
    #pragma unroll
    for (int nt = 0; nt < 2; ++nt) {
        lsum[nt] += __shfl_xor(lsum[nt], 16, 64);
        lsum[nt] += __shfl_xor(lsum[nt], 32, 64);
    }
    __syncthreads();                              // all tile reads done; LDS reusable
    float* Obuf = (float*)LDSB;                   // [qq][f 64][q 32+1 pad] = 33792 B
    float* Lbuf = (float*)(LDSB + 33792);         // [qq][q 32] = 512 B
    if (kv == 1) {
        #pragma unroll
        for (int ft = 0; ft < 4; ++ft)
            #pragma unroll
            for (int nt = 0; nt < 2; ++nt)
                #pragma unroll
                for (int r = 0; r < 4; ++r)
                    Obuf[qq * 2112 + (ft * 16 + g * 4 + r) * 33 + nt * 16 + a] = oacc[ft][nt][r];
        if (g == 0)
            #pragma unroll
            for (int nt = 0; nt < 2; ++nt)
                Lbuf[qq * 32 + nt * 16 + a] = lsum[nt];
    }
    __syncthreads();
    if (kv == 0) {
        #pragma unroll
        for (int nt = 0; nt < 2; ++nt) {
            const float inv = 1.f / (lsum[nt] + Lbuf[qq * 32 + nt * 16 + a]);
            float* op = out + ((size_t)b * SS + qrow0 + nt * 16 + a) * DD + h * HD;
            #pragma unroll
            for (int ft = 0; ft < 4; ++ft) {
                const int fb = ft * 16 + g * 4;
                float4 vv = {
                    (oacc[ft][nt][0] + Obuf[qq * 2112 + (fb + 0) * 33 + nt * 16 + a]) * inv,
                    (oacc[ft][nt][1] + Obuf[qq * 2112 + (fb + 1) * 33 + nt * 16 + a]) * inv,
                    (oacc[ft][nt][2] + Obuf[qq * 2112 + (fb + 2) * 33 + nt * 16 + a]) * inv,
                    (oacc[ft][nt][3] + Obuf[qq * 2112 + (fb + 3) * 33 + nt * 16 + a]) * inv };
                *(float4*)(op + fb) = vv;
            }
        }
    }
}

extern "C" void kernel_launch(void* const* d_in, const int* in_sizes, int n_in,
                              void* d_out, int out_size, void* d_ws, size_t ws_size,
                              hipStream_t stream) {
    const float* x  = (const float*)d_in[0];
    const float* wq = (const float*)d_in[1];
    float* out = (float*)d_out;
    unsigned short* q_h = (unsigned short*)d_ws;   // 8 MB

    dim3 ggrid(128, 8);
    gemm_kernel<<<ggrid, 256, 0, stream>>>(x, wq, q_h);
    attn_kernel<<<512, 512, 0, stream>>>((const __half*)q_h, out);
}

// Round 4
// 126.532 us; speedup vs baseline: 1.1389x; 1.0164x over previous
//
#include <hip/hip_runtime.h>
#include <hip/hip_fp16.h>
#include <math.h>

#define SS 2048
#define DD 512
#define NH 8
#define HD 64

typedef __attribute__((ext_vector_type(8))) short frag_ab;     // 8 fp16 (x32 A/B)
typedef __attribute__((ext_vector_type(4))) float frag_cd;     // 4 fp32 (C/D)
typedef __attribute__((ext_vector_type(4))) _Float16 frag_b4;  // 4 fp16 (x16 A/B)

static __device__ inline unsigned int pack_h2(float x, float y) {
    __half2 t = __floats2half2_rn(x, y);   // x -> low half
    return *(unsigned int*)&t;
}

// ---------- GEMM: q_h = fp16(x @ Wq); B transposed in-register during staging ----------
__global__ __launch_bounds__(256, 4) void gemm_kernel(const float* __restrict__ x,
                                                      const float* __restrict__ w,
                                                      unsigned short* __restrict__ q) {
    __shared__ __align__(16) unsigned short Ah[2][64 * 72];  // [m][k]
    __shared__ __align__(16) unsigned short Bt[2][64 * 72];  // [n][k]
    const int tid = threadIdx.x;
    const int lane = tid & 63, wv = tid >> 6;
    const int a = lane & 15, g = lane >> 4;
    const int bm = blockIdx.x, bn = blockIdx.y;

    frag_cd acc[4] = {};
    const int asr = tid >> 4;
    const int ac4 = (tid & 15) * 4;
    const int bnn = (tid & 31) * 2;
    const int bkk = (tid >> 5) * 8;

    float4 av[4];
    float2 bv[8];
    #pragma unroll
    for (int p = 0; p < 4; ++p)
        av[p] = *(const float4*)(x + (size_t)(bm * 64 + asr + p * 16) * 512 + ac4);
    #pragma unroll
    for (int j = 0; j < 8; ++j)
        bv[j] = *(const float2*)(w + (size_t)(bkk + j) * 512 + bn * 64 + bnn);

    for (int it = 0; it < 8; ++it) {
        const int cur = it & 1;
        #pragma unroll
        for (int p = 0; p < 4; ++p) {
            uint2 hh = { pack_h2(av[p].x, av[p].y), pack_h2(av[p].z, av[p].w) };
            *(uint2*)&Ah[cur][(asr + p * 16) * 72 + ac4] = hh;
        }
        {
            unsigned int t0[4], t1[4];
            #pragma unroll
            for (int j = 0; j < 4; ++j) {
                t0[j] = pack_h2(bv[2 * j].x, bv[2 * j + 1].x);
                t1[j] = pack_h2(bv[2 * j].y, bv[2 * j + 1].y);
            }
            *(uint4*)&Bt[cur][bnn * 72 + bkk]       = *(uint4*)t0;
            *(uint4*)&Bt[cur][(bnn + 1) * 72 + bkk] = *(uint4*)t1;
        }
        __syncthreads();
        if (it < 7) {
            const int k0 = (it + 1) * 64;
            #pragma unroll
            for (int p = 0; p < 4; ++p)
                av[p] = *(const float4*)(x + (size_t)(bm * 64 + asr + p * 16) * 512 + k0 + ac4);
            #pragma unroll
            for (int j = 0; j < 8; ++j)
                bv[j] = *(const float2*)(w + (size_t)(k0 + bkk + j) * 512 + bn * 64 + bnn);
        }
        #pragma unroll
        for (int kh = 0; kh < 2; ++kh) {
            const frag_ab bf = *(const frag_ab*)&Bt[cur][(wv * 16 + a) * 72 + kh * 32 + g * 8];
            #pragma unroll
            for (int mt = 0; mt < 4; ++mt) {
                const frag_ab af = *(const frag_ab*)&Ah[cur][(mt * 16 + a) * 72 + kh * 32 + g * 8];
                acc[mt] = __builtin_amdgcn_mfma_f32_16x16x32_f16(af, bf, acc[mt], 0, 0, 0);
            }
        }
    }
    #pragma unroll
    for (int mt = 0; mt < 4; ++mt)
        #pragma unroll
        for (int r = 0; r < 4; ++r) {
            const int m = bm * 64 + mt * 16 + g * 4 + r;
            const int n = bn * 64 + wv * 16 + a;
            __half hv = __float2half_rn(acc[mt][r]);
            q[(size_t)m * 512 + n] = *(unsigned short*)&hv;
        }
}

// ---------- Flash attention, R14: P stays in registers via K=16 PV MFMAs ----------
// Grid 512 = 16(qt of 128 q-rows) x 8(h) x 4(b); 512 threads = 8 waves =
// 4 q-groups(32 rows, nt=0,1) x 2 key-halves (1024 keys each).
// Core idea: the QK^T C/D fragment layout (row = 4g+r = key, col = a = q) is
// IDENTICAL to the B-operand layout of mfma_f32_16x16x16f16 (k = 4g+j, col = a).
// So exp2(S^T) packed to fp16 pairs is directly the PV B-fragment for a
// 16-key slice: PV = 4 kt-slices of K=16 MFMAs.  No P transpose, no Pq LDS,
// no cross-lane ops (R10's Pq roundtrip = 12 LDS ops/iter; R13's shuffle =
// 16 ds_bpermute/iter -- both on the saturated LDS pipe).
//  * V^T A-frag (x16): lane(a,g) reads V^T[f=ft*16+a][key=16kt+4g..+3] = b64
//    from swizzled Vt; banks: 8 distinct pair-groups x 2 lanes = free.
//  * LDS 34816 B (Kt 18432 + Vt 16384); epilogue Obuf/Lbuf overlaid.
//  * __launch_bounds__(512,4): 128-reg cap, no spill (R12's (512,8) spilled).
__global__ __launch_bounds__(512, 4) void attn_kernel(const __half* __restrict__ qg,
                                                      float* __restrict__ out) {
    __shared__ __align__(16) unsigned char LDSB[34816];
    unsigned short* KtB = (unsigned short*)LDSB;            // [2][64*72]  18432 B
    unsigned short* VtB = (unsigned short*)(LDSB + 18432);  // [2][64*64]  16384 B

    const int tid = threadIdx.x;
    const int lane = tid & 63, wv = tid >> 6;
    const int a = lane & 15, g = lane >> 4;
    const int qq = wv & 3;            // q group (32 rows)
    const int kv = wv >> 2;           // key half (1024 keys)
    const int bid = blockIdx.x;       // 512 = 16(qt) * 8(h) * 4(b)
    const int qt = bid & 15;
    const int h  = (bid >> 4) & 7;
    const int b  = bid >> 7;

    const unsigned short* qbh = (const unsigned short*)qg + (size_t)b * SS * DD + h * HD;
    const int qrow0 = qt * 128 + qq * 32;

    // Q B-fragments, pre-scaled by 0.125*log2(e)
    frag_ab qf[2][2];
    const __half2 qsc = __float2half2_rn(0.18033688011112042f);
    #pragma unroll
    for (int nt = 0; nt < 2; ++nt)
        #pragma unroll
        for (int kh = 0; kh < 2; ++kh) {
            frag_ab t = *(const frag_ab*)(qbh + (size_t)(qrow0 + nt * 16 + a) * DD + kh * 32 + g * 8);
            __half2* phh = (__half2*)&t;
            #pragma unroll
            for (int i = 0; i < 4; ++i) phh[i] = __hmul2(phh[i], qsc);
            qf[nt][kh] = t;
        }

    frag_cd oacc[4][2] = {};          // [ft][nt] -> O^T[feature][q=a]
    float lsum[2] = {0.f, 0.f};

    // staging: threads 0-255 stage key-half 0, 256-511 half 1 (== own wave's kv)
    const int t8 = tid & 255;
    const int f0 = (t8 & 31) * 2;     // feature column (even)
    const int u8 = t8 >> 5;           // key chunk 0..7
    const int r0 = u8 * 8;
    const int keybase = (tid >> 8) * 1024;
    unsigned short* Ks = KtB + (tid >> 8) * 4608;
    unsigned short* Vs = VtB + (tid >> 8) * 4096;
    const int vsw = (u8 ^ (t8 & 7)) << 3;   // s(f) = (f>>1)&7 ; (f0>>1)&7 == t8&7

    unsigned int d[8];
    #pragma unroll
    for (int k = 0; k < 8; ++k)
        d[k] = *(const unsigned int*)(qbh + (size_t)(keybase + r0 + k) * DD + f0);

    const unsigned short* Kc = KtB + kv * 4608;
    const unsigned short* Vc = VtB + kv * 4096;
    const float coff = -11.541560327111707f;   // -8*log2(e): p = 2^(s' + coff) = e^(s-8)
    const int sv = (a >> 1) & 7;               // V read swizzle: s(f)= (f>>1)&7, f=ft*16+a

    for (int it = 0; it < 16; ++it) {
        __syncthreads();              // all waves done reading previous tiles
        #pragma unroll
        for (int k = 0; k < 8; ++k)   // K key-major, stride 72 (floor-rate)
            *(unsigned int*)&Ks[(r0 + k) * 72 + f0] = d[k];
        {                             // V^T feature-major, stride 64 + XOR swizzle
            unsigned int vlo[4], vhi[4];
            #pragma unroll
            for (int j = 0; j < 4; ++j) {
                vlo[j] = (d[2 * j] & 0xFFFFu) | (d[2 * j + 1] << 16);
                vhi[j] = (d[2 * j] >> 16)     | (d[2 * j + 1] & 0xFFFF0000u);
            }
            *(uint4*)&Vs[f0 * 64 + vsw]       = *(uint4*)vlo;   // same s for f0,f0+1
            *(uint4*)&Vs[(f0 + 1) * 64 + vsw] = *(uint4*)vhi;
        }
        __syncthreads();              // staged tiles visible

        if (it + 1 < 16) {            // prefetch next tile (overlaps compute)
            const int kb = keybase + (it + 1) * 64;
            #pragma unroll
            for (int k = 0; k < 8; ++k)
                d[k] = *(const unsigned int*)(qbh + (size_t)(kb + r0 + k) * DD + f0);
        }

        // ---- per 16-key slice: S^T = K.Q^T -> exp2 -> pack == PV B-frag -> PV ----
        #pragma unroll
        for (int kt = 0; kt < 4; ++kt) {
            const frag_ab ka0 = *(const frag_ab*)&Kc[(kt * 16 + a) * 72 + g * 8];
            const frag_ab ka1 = *(const frag_ab*)&Kc[(kt * 16 + a) * 72 + 32 + g * 8];
            frag_b4 pbk[2];
            #pragma unroll
            for (int nt = 0; nt < 2; ++nt) {
                frag_cd c = {coff, coff, coff, coff};
                c = __builtin_amdgcn_mfma_f32_16x16x32_f16(ka0, qf[nt][0], c, 0, 0, 0);
                c = __builtin_amdgcn_mfma_f32_16x16x32_f16(ka1, qf[nt][1], c, 0, 0, 0);
                const float p0 = __builtin_amdgcn_exp2f(c[0]);
                const float p1 = __builtin_amdgcn_exp2f(c[1]);
                const float p2 = __builtin_amdgcn_exp2f(c[2]);
                const float p3 = __builtin_amdgcn_exp2f(c[3]);
                lsum[nt] += (p0 + p1) + (p2 + p3);
                union { unsigned int u[2]; frag_b4 h; } pu;
                pu.u[0] = pack_h2(p0, p1);   // keys 16kt+4g+0,1  (B-frag k=4g+0,1)
                pu.u[1] = pack_h2(p2, p3);   // keys 16kt+4g+2,3  (B-frag k=4g+2,3)
                pbk[nt] = pu.h;
            }
            // V^T A-frags for this 16-key slice: keys 16kt+4g..+3 at feature ft*16+a
            const int vch = ((2 * kt + (g >> 1)) ^ sv) << 3;   // swizzled 8-key chunk
            const int vof = (g & 1) << 2;                      // 4-key offset in chunk
            #pragma unroll
            for (int ft = 0; ft < 4; ++ft) {
                const frag_b4 va = *(const frag_b4*)&Vc[(ft * 16 + a) * 64 + vch + vof];
                oacc[ft][0] = __builtin_amdgcn_mfma_f32_16x16x16f16(va, pbk[0], oacc[ft][0], 0, 0, 0);
                oacc[ft][1] = __builtin_amdgcn_mfma_f32_16x16x16f16(va, pbk[1], oacc[ft][1], 0, 0, 0);
            }
        }
    }

    // ---- in-block combine: kv=1 -> LDS; kv=0 adds, normalizes, writes ----
    #pragma unroll
    for (int nt = 0; nt < 2; ++nt) {
        lsum[nt] += __shfl_xor(lsum[nt], 16, 64);
        lsum[nt] += __shfl_xor(lsum[nt], 32, 64);
    }
    __syncthreads();                              // all tile reads done; LDS reusable
    float* Obuf = (float*)LDSB;                   // [qq][f 64][q 32+1 pad] = 33792 B
    float* Lbuf = (float*)(LDSB + 33792);         // [qq][q 32] = 512 B
    if (kv == 1) {
        #pragma unroll
        for (int ft = 0; ft < 4; ++ft)
            #pragma unroll
            for (int nt = 0; nt < 2; ++nt)
                #pragma unroll
                for (int r = 0; r < 4; ++r)
                    Obuf[qq * 2112 + (ft * 16 + g * 4 + r) * 33 + nt * 16 + a] = oacc[ft][nt][r];
        if (g == 0)
            #pragma unroll
            for (int nt = 0; nt < 2; ++nt)
                Lbuf[qq * 32 + nt * 16 + a] = lsum[nt];
    }
    __syncthreads();
    if (kv == 0) {
        #pragma unroll
        for (int nt = 0; nt < 2; ++nt) {
            const float inv = 1.f / (lsum[nt] + Lbuf[qq * 32 + nt * 16 + a]);
            float* op = out + ((size_t)b * SS + qrow0 + nt * 16 + a) * DD + h * HD;
            #pragma unroll
            for (int ft = 0; ft < 4; ++ft) {
                const int fb = ft * 16 + g * 4;
                float4 vv = {
                    (oacc[ft][nt][0] + Obuf[qq * 2112 + (fb + 0) * 33 + nt * 16 + a]) * inv,
                    (oacc[ft][nt][1] + Obuf[qq * 2112 + (fb + 1) * 33 + nt * 16 + a]) * inv,
                    (oacc[ft][nt][2] + Obuf[qq * 2112 + (fb + 2) * 33 + nt * 16 + a]) * inv,
                    (oacc[ft][nt][3] + Obuf[qq * 2112 + (fb + 3) * 33 + nt * 16 + a]) * inv };
                *(float4*)(op + fb) = vv;
            }
        }
    }
}

extern "C" void kernel_launch(void* const* d_in, const int* in_sizes, int n_in,
                              void* d_out, int out_size, void* d_ws, size_t ws_size,
                              hipStream_t stream) {
    const float* x  = (const float*)d_in[0];
    const float* wq = (const float*)d_in[1];
    float* out = (float*)d_out;
    unsigned short* q_h = (unsigned short*)d_ws;   // 8 MB

    dim3 ggrid(128, 8);
    gemm_kernel<<<ggrid, 256, 0, stream>>>(x, wq, q_h);
    attn_kernel<<<512, 512, 0, stream>>>((const __half*)q_h, out);
}

// Round 5
// 122.611 us; speedup vs baseline: 1.1754x; 1.0320x over previous
//
#include <hip/hip_runtime.h>
#include <hip/hip_fp16.h>
#include <math.h>

#define SS 2048
#define DD 512
#define NH 8
#define HD 64

typedef __attribute__((ext_vector_type(8))) short frag_ab;     // 8 fp16 (x32 A/B)
typedef __attribute__((ext_vector_type(4))) float frag_cd;     // 4 fp32 (C/D)
typedef __attribute__((ext_vector_type(4))) _Float16 frag_b4;  // 4 fp16 (x16 A/B)

static __device__ inline unsigned int pack_h2(float x, float y) {
    __half2 t = __floats2half2_rn(x, y);   // x -> low half
    return *(unsigned int*)&t;
}

// ---------- GEMM v2: q_h = fp16(x @ Wq) ----------
// R15: 128x128 tiles (was 64x64).  Grid 256 = (64 bm, 4 bn) = exactly 1
// block/CU; 512 threads = 8 waves (2 row-groups x 4 col-groups, wave tile
// 64x32).  K-step 64, double-buffered LDS, ONE barrier/iter with the
// decoupled schedule: stage tile it+1 (regs->LDS) || compute tile it,
// prefetch tile it+2 (global->regs).  L2 traffic halves vs 64x64 (A and W
// each read 4x less); 2x MFMA work per barrier.
__global__ __launch_bounds__(512, 2) void gemm_kernel(const float* __restrict__ x,
                                                      const float* __restrict__ w,
                                                      unsigned short* __restrict__ q) {
    __shared__ __align__(16) unsigned short Ah[2][128 * 72];  // [m][k] 36.9 KB
    __shared__ __align__(16) unsigned short Bt[2][128 * 72];  // [n][k] 36.9 KB
    const int tid = threadIdx.x;
    const int lane = tid & 63, wv = tid >> 6;
    const int a = lane & 15, g = lane >> 4;
    const int bm = blockIdx.x, bn = blockIdx.y;
    const int wr = wv >> 2, wc = wv & 3;     // wave tile: rows 64*wr.., cols 32*wc..

    frag_cd acc[4][2] = {};                  // [mt][nt]
    // A staging: thread -> row tid>>2 (0..127), k-seg (tid&3)*16
    const int ar = tid >> 2;
    const int ak = (tid & 3) * 16;
    // B staging: thread -> n-pair (tid&63)*2, k-chunk (tid>>6)*8
    const int bnn = (tid & 63) * 2;
    const int bkk = (tid >> 6) * 8;

    float4 av[4];
    float2 bv[8];

    auto load_tiles = [&](int k0) {
        #pragma unroll
        for (int i = 0; i < 4; ++i)
            av[i] = *(const float4*)(x + (size_t)(bm * 128 + ar) * 512 + k0 + ak + 4 * i);
        #pragma unroll
        for (int j = 0; j < 8; ++j)
            bv[j] = *(const float2*)(w + (size_t)(k0 + bkk + j) * 512 + bn * 128 + bnn);
    };
    auto stage_tiles = [&](int buf) {
        unsigned int ha[8];
        #pragma unroll
        for (int i = 0; i < 4; ++i) {
            ha[2 * i]     = pack_h2(av[i].x, av[i].y);
            ha[2 * i + 1] = pack_h2(av[i].z, av[i].w);
        }
        *(uint4*)&Ah[buf][ar * 72 + ak]     = *(uint4*)&ha[0];
        *(uint4*)&Ah[buf][ar * 72 + ak + 8] = *(uint4*)&ha[4];
        unsigned int t0[4], t1[4];
        #pragma unroll
        for (int j = 0; j < 4; ++j) {
            t0[j] = pack_h2(bv[2 * j].x, bv[2 * j + 1].x);
            t1[j] = pack_h2(bv[2 * j].y, bv[2 * j + 1].y);
        }
        *(uint4*)&Bt[buf][bnn * 72 + bkk]       = *(uint4*)t0;
        *(uint4*)&Bt[buf][(bnn + 1) * 72 + bkk] = *(uint4*)t1;
    };

    load_tiles(0);
    stage_tiles(0);                 // tile 0 -> buf 0
    load_tiles(64);                 // tile 1 -> regs
    __syncthreads();

    for (int it = 0; it < 8; ++it) {
        const int cur = it & 1;
        if (it < 7) stage_tiles(cur ^ 1);          // tile it+1 -> other buf
        if (it < 6) load_tiles((it + 2) * 64);     // tile it+2 -> regs
        #pragma unroll
        for (int kh = 0; kh < 2; ++kh) {
            frag_ab bf[2], af[4];
            #pragma unroll
            for (int nt = 0; nt < 2; ++nt)
                bf[nt] = *(const frag_ab*)&Bt[cur][(wc * 32 + nt * 16 + a) * 72 + kh * 32 + g * 8];
            #pragma unroll
            for (int mt = 0; mt < 4; ++mt)
                af[mt] = *(const frag_ab*)&Ah[cur][(wr * 64 + mt * 16 + a) * 72 + kh * 32 + g * 8];
            #pragma unroll
            for (int mt = 0; mt < 4; ++mt)
                #pragma unroll
                for (int nt = 0; nt < 2; ++nt)
                    acc[mt][nt] = __builtin_amdgcn_mfma_f32_16x16x32_f16(af[mt], bf[nt], acc[mt][nt], 0, 0, 0);
        }
        __syncthreads();
    }
    #pragma unroll
    for (int mt = 0; mt < 4; ++mt)
        #pragma unroll
        for (int nt = 0; nt < 2; ++nt)
            #pragma unroll
            for (int r = 0; r < 4; ++r) {
                const int m = bm * 128 + wr * 64 + mt * 16 + g * 4 + r;
                const int n = bn * 128 + wc * 32 + nt * 16 + a;
                __half hv = __float2half_rn(acc[mt][nt][r]);
                q[(size_t)m * 512 + n] = *(unsigned short*)&hv;
            }
}

// ---------- Flash attention, R15 = R14 compute + double-buffered tiles ----------
// Grid 512 = 16(qt of 128 q-rows) x 8(h) x 4(b); 512 threads = 8 waves =
// 4 q-groups(32 rows, nt=0,1) x 2 key-halves (1024 keys each).
//  * R14 (verified): P stays in registers -- QK^T C/D fragment layout equals
//    the B-operand layout of mfma_f32_16x16x16f16, so exp2(S^T) packed to
//    fp16 IS the PV B-frag.  No transpose, no Pq.
//  * R15: Kt/Vt double-buffered across iterations (LDS 34816 -> 69632 B;
//    grid gives 2 blocks/CU and 160K/69.6K = 2 -- no occupancy change).
//    ONE barrier per iter (was two): stage tile it+1 -> buf^1 at top of
//    iter (overlaps compute of tile it from buf), barrier at end separates
//    iterations.  Writes never touch the buffer being read.
__global__ __launch_bounds__(512, 4) void attn_kernel(const __half* __restrict__ qg,
                                                      float* __restrict__ out) {
    __shared__ __align__(16) unsigned char LDSB[69632];
    unsigned short* KtB = (unsigned short*)LDSB;            // [2 buf][2 kv][64*72] 36864 B
    unsigned short* VtB = (unsigned short*)(LDSB + 36864);  // [2 buf][2 kv][64*64] 32768 B

    const int tid = threadIdx.x;
    const int lane = tid & 63, wv = tid >> 6;
    const int a = lane & 15, g = lane >> 4;
    const int qq = wv & 3;            // q group (32 rows)
    const int kv = wv >> 2;           // key half (1024 keys)
    const int bid = blockIdx.x;       // 512 = 16(qt) * 8(h) * 4(b)
    const int qt = bid & 15;
    const int h  = (bid >> 4) & 7;
    const int b  = bid >> 7;

    const unsigned short* qbh = (const unsigned short*)qg + (size_t)b * SS * DD + h * HD;
    const int qrow0 = qt * 128 + qq * 32;

    // Q B-fragments, pre-scaled by 0.125*log2(e)
    frag_ab qf[2][2];
    const __half2 qsc = __float2half2_rn(0.18033688011112042f);
    #pragma unroll
    for (int nt = 0; nt < 2; ++nt)
        #pragma unroll
        for (int kh = 0; kh < 2; ++kh) {
            frag_ab t = *(const frag_ab*)(qbh + (size_t)(qrow0 + nt * 16 + a) * DD + kh * 32 + g * 8);
            __half2* phh = (__half2*)&t;
            #pragma unroll
            for (int i = 0; i < 4; ++i) phh[i] = __hmul2(phh[i], qsc);
            qf[nt][kh] = t;
        }

    frag_cd oacc[4][2] = {};          // [ft][nt] -> O^T[feature][q=a]
    float lsum[2] = {0.f, 0.f};

    // staging: threads 0-255 stage key-half 0, 256-511 half 1 (== own wave's kv)
    const int t8 = tid & 255;
    const int f0 = (t8 & 31) * 2;     // feature column (even)
    const int u8 = t8 >> 5;           // key chunk 0..7
    const int r0 = u8 * 8;
    const int keybase = (tid >> 8) * 1024;
    unsigned short* KsBase = KtB + (tid >> 8) * 4608;
    unsigned short* VsBase = VtB + (tid >> 8) * 4096;
    const int vsw = (u8 ^ (t8 & 7)) << 3;   // s(f) = (f>>1)&7 ; (f0>>1)&7 == t8&7

    unsigned int d[8];
    #pragma unroll
    for (int k = 0; k < 8; ++k)
        d[k] = *(const unsigned int*)(qbh + (size_t)(keybase + r0 + k) * DD + f0);

    const unsigned short* KcBase = KtB + kv * 4608;
    const unsigned short* VcBase = VtB + kv * 4096;
    const float coff = -11.541560327111707f;   // -8*log2(e): p = 2^(s' + coff) = e^(s-8)
    const int sv = (a >> 1) & 7;               // V read swizzle: s(f)=(f>>1)&7, f=ft*16+a

    auto stage_write = [&](int buf) {
        unsigned short* Ksb = KsBase + buf * 9216;
        unsigned short* Vsb = VsBase + buf * 8192;
        #pragma unroll
        for (int k = 0; k < 8; ++k)   // K key-major, stride 72 (floor-rate)
            *(unsigned int*)&Ksb[(r0 + k) * 72 + f0] = d[k];
        unsigned int vlo[4], vhi[4];
        #pragma unroll
        for (int j = 0; j < 4; ++j) {
            vlo[j] = (d[2 * j] & 0xFFFFu) | (d[2 * j + 1] << 16);
            vhi[j] = (d[2 * j] >> 16)     | (d[2 * j + 1] & 0xFFFF0000u);
        }
        *(uint4*)&Vsb[f0 * 64 + vsw]       = *(uint4*)vlo;   // same s for f0,f0+1
        *(uint4*)&Vsb[(f0 + 1) * 64 + vsw] = *(uint4*)vhi;
    };

    stage_write(0);                   // tile 0 -> buf 0
    #pragma unroll
    for (int k = 0; k < 8; ++k)       // tile 1 -> regs
        d[k] = *(const unsigned int*)(qbh + (size_t)(keybase + 64 + r0 + k) * DD + f0);
    __syncthreads();

    for (int it = 0; it < 16; ++it) {
        const int cur = it & 1;
        if (it < 15) stage_write(cur ^ 1);     // tile it+1 -> other buf
        if (it < 14) {                          // tile it+2 -> regs
            const int kb = keybase + (it + 2) * 64;
            #pragma unroll
            for (int k = 0; k < 8; ++k)
                d[k] = *(const unsigned int*)(qbh + (size_t)(kb + r0 + k) * DD + f0);
        }
        const unsigned short* Kc = KcBase + cur * 9216;
        const unsigned short* Vc = VcBase + cur * 8192;

        // ---- per 16-key slice: S^T = K.Q^T -> exp2 -> pack == PV B-frag -> PV ----
        #pragma unroll
        for (int kt = 0; kt < 4; ++kt) {
            const frag_ab ka0 = *(const frag_ab*)&Kc[(kt * 16 + a) * 72 + g * 8];
            const frag_ab ka1 = *(const frag_ab*)&Kc[(kt * 16 + a) * 72 + 32 + g * 8];
            frag_b4 pbk[2];
            #pragma unroll
            for (int nt = 0; nt < 2; ++nt) {
                frag_cd c = {coff, coff, coff, coff};
                c = __builtin_amdgcn_mfma_f32_16x16x32_f16(ka0, qf[nt][0], c, 0, 0, 0);
                c = __builtin_amdgcn_mfma_f32_16x16x32_f16(ka1, qf[nt][1], c, 0, 0, 0);
                const float p0 = __builtin_amdgcn_exp2f(c[0]);
                const float p1 = __builtin_amdgcn_exp2f(c[1]);
                const float p2 = __builtin_amdgcn_exp2f(c[2]);
                const float p3 = __builtin_amdgcn_exp2f(c[3]);
                lsum[nt] += (p0 + p1) + (p2 + p3);
                union { unsigned int u[2]; frag_b4 h; } pu;
                pu.u[0] = pack_h2(p0, p1);   // keys 16kt+4g+0,1  (B-frag k=4g+0,1)
                pu.u[1] = pack_h2(p2, p3);   // keys 16kt+4g+2,3  (B-frag k=4g+2,3)
                pbk[nt] = pu.h;
            }
            // V^T A-frags for this 16-key slice: keys 16kt+4g..+3 at feature ft*16+a
            const int vch = ((2 * kt + (g >> 1)) ^ sv) << 3;   // swizzled 8-key chunk
            const int vof = (g & 1) << 2;                      // 4-key offset in chunk
            #pragma unroll
            for (int ft = 0; ft < 4; ++ft) {
                const frag_b4 va = *(const frag_b4*)&Vc[(ft * 16 + a) * 64 + vch + vof];
                oacc[ft][0] = __builtin_amdgcn_mfma_f32_16x16x16f16(va, pbk[0], oacc[ft][0], 0, 0, 0);
                oacc[ft][1] = __builtin_amdgcn_mfma_f32_16x16x16f16(va, pbk[1], oacc[ft][1], 0, 0, 0);
            }
        }
        __syncthreads();              // separates iterations (buffers alternate)
    }

    // ---- in-block combine: kv=1 -> LDS; kv=0 adds, normalizes, writes ----
    #pragma unroll
    for (int nt = 0; nt < 2; ++nt) {
        lsum[nt] += __shfl_xor(lsum[nt], 16, 64);
        lsum[nt] += __shfl_xor(lsum[nt], 32, 64);
    }
    float* Obuf = (float*)LDSB;                   // [qq][f 64][q 32+1 pad] = 33792 B
    float* Lbuf = (float*)(LDSB + 33792);         // [qq][q 32] = 512 B
    if (kv == 1) {
        #pragma unroll
        for (int ft = 0; ft < 4; ++ft)
            #pragma unroll
            for (int nt = 0; nt < 2; ++nt)
                #pragma unroll
                for (int r = 0; r < 4; ++r)
                    Obuf[qq * 2112 + (ft * 16 + g * 4 + r) * 33 + nt * 16 + a] = oacc[ft][nt][r];
        if (g == 0)
            #pragma unroll
            for (int nt = 0; nt < 2; ++nt)
                Lbuf[qq * 32 + nt * 16 + a] = lsum[nt];
    }
    __syncthreads();
    if (kv == 0) {
        #pragma unroll
        for (int nt = 0; nt < 2; ++nt) {
            const float inv = 1.f / (lsum[nt] + Lbuf[qq * 32 + nt * 16 + a]);
            float* op = out + ((size_t)b * SS + qrow0 + nt * 16 + a) * DD + h * HD;
            #pragma unroll
            for (int ft = 0; ft < 4; ++ft) {
                const int fb = ft * 16 + g * 4;
                float4 vv = {
                    (oacc[ft][nt][0] + Obuf[qq * 2112 + (fb + 0) * 33 + nt * 16 + a]) * inv,
                    (oacc[ft][nt][1] + Obuf[qq * 2112 + (fb + 1) * 33 + nt * 16 + a]) * inv,
                    (oacc[ft][nt][2] + Obuf[qq * 2112 + (fb + 2) * 33 + nt * 16 + a]) * inv,
                    (oacc[ft][nt][3] + Obuf[qq * 2112 + (fb + 3) * 33 + nt * 16 + a]) * inv };
                *(float4*)(op + fb) = vv;
            }
        }
    }
}

extern "C" void kernel_launch(void* const* d_in, const int* in_sizes, int n_in,
                              void* d_out, int out_size, void* d_ws, size_t ws_size,
                              hipStream_t stream) {
    const float* x  = (const float*)d_in[0];
    const float* wq = (const float*)d_in[1];
    float* out = (float*)d_out;
    unsigned short* q_h = (unsigned short*)d_ws;   // 8 MB

    dim3 ggrid(64, 4);
    gemm_kernel<<<ggrid, 512, 0, stream>>>(x, wq, q_h);
    attn_kernel<<<512, 512, 0, stream>>>((const __half*)q_h, out);
}